// Round 7
// baseline (562.368 us; speedup 1.0000x reference)
//
#include <hip/hip_runtime.h>
#include <stdint.h>

// NARM fused pipeline v7 for MI355X (gfx950).
// Software-pipelined launches: launch for chunk c runs THREE roles in one grid:
//   blocks   0..127 : scan chunk c        (writes hl/hg parity c&1)
//   blocks 128..191 : score+cum chunk c-1 (reads parity (c-1)&1) -- hidden
//   blocks 192..255 : xcast chunk c+1     (x fp32 -> xb bf16 fragment layout)
// Launch boundaries provide producer->consumer ordering; hl/hg double-buffered.
// h_seq/xb fragment layout: off(t,b,k) = t*131072 + (b>>4)*2048 + (k>>3)*128 + (b&15)*8 + (k&7)

typedef __attribute__((ext_vector_type(8))) short short8;
typedef __attribute__((ext_vector_type(4))) float float4v;

#define LDS_BARRIER() asm volatile("s_waitcnt lgkmcnt(0)\n\ts_barrier" ::: "memory")

__device__ inline float bf2f(unsigned short u){
  union { unsigned int i; float f; } v; v.i = ((unsigned int)u) << 16; return v.f;
}
__device__ inline unsigned short f2bf(float f){
  union { float f; unsigned int i; } v; v.f = f;
  unsigned int x = v.i;
  return (unsigned short)((x + 0x7fffu + ((x >> 16) & 1u)) >> 16);
}
__device__ inline float sigm(float x){ return __builtin_amdgcn_rcpf(1.0f + __expf(-x)); }

// ================= scan body (blocks 0..127) =================
__device__ __forceinline__ void scan_body(
    unsigned short* hb,                      // LDS, 2*2048 shorts
    const unsigned short* __restrict__ xb,
    const float* __restrict__ Wih_g, const float* __restrict__ Whh_g,
    const float* __restrict__ bih_g, const float* __restrict__ bhh_g,
    const float* __restrict__ Wih_l, const float* __restrict__ Whh_l,
    const float* __restrict__ bih_l, const float* __restrict__ bhh_l,
    unsigned short* __restrict__ wrseq,      // this chunk's parity buffer
    const unsigned short* __restrict__ prevseq, // previous parity (carry)
    int tc, int t0, int bid, int tid)
{
  int w = tid >> 6, L = tid & 63, l15 = L & 15, q = L >> 4;
  int gru = bid & 1;
  int bg = bid >> 1;
  const float* Wih = gru ? Wih_l : Wih_g;
  const float* Whh = gru ? Whh_l : Whh_g;
  const float* bih = gru ? bih_l : bih_g;
  const float* bhh = gru ? bhh_l : bhh_g;

  int col = w * 16 + l15;
  int cch = w * 2 + (l15 >> 3);
  int cj  = l15 & 7;

  short8 Wi[3][4], Wh[3][4];
  #pragma unroll
  for (int G = 0; G < 3; G++) {
    int row = G * 128 + col;
    #pragma unroll
    for (int kf = 0; kf < 4; kf++) {
      const float4* p0 = (const float4*)(Wih + (size_t)row * 128 + kf * 32 + q * 8);
      const float4* p1 = (const float4*)(Whh + (size_t)row * 128 + kf * 32 + q * 8);
      float4 a0 = p0[0], a1 = p0[1], b0f = p1[0], b1f = p1[1];
      short8 si, sh;
      si[0]=(short)f2bf(a0.x); si[1]=(short)f2bf(a0.y); si[2]=(short)f2bf(a0.z); si[3]=(short)f2bf(a0.w);
      si[4]=(short)f2bf(a1.x); si[5]=(short)f2bf(a1.y); si[6]=(short)f2bf(a1.z); si[7]=(short)f2bf(a1.w);
      sh[0]=(short)f2bf(b0f.x); sh[1]=(short)f2bf(b0f.y); sh[2]=(short)f2bf(b0f.z); sh[3]=(short)f2bf(b0f.w);
      sh[4]=(short)f2bf(b1f.x); sh[5]=(short)f2bf(b1f.y); sh[6]=(short)f2bf(b1f.z); sh[7]=(short)f2bf(b1f.w);
      Wi[G][kf] = si; Wh[G][kf] = sh;
    }
  }
  float br  = bih[col]       + bhh[col];
  float bz  = bih[128 + col] + bhh[128 + col];
  float bin = bih[256 + col];               // bhh_n stays inside r*( ) per PyTorch GRU
  float bnh = bhh[256 + col];

  float hold[4];
  #pragma unroll
  for (int r = 0; r < 4; r++) {
    int m = q * 4 + r;
    unsigned short u = prevseq[(size_t)(tc - 1) * 131072 + (size_t)bg * 2048 + cch * 128 + m * 8 + cj];
    hold[r] = bf2f(u);
    hb[cch * 128 + m * 8 + cj] = u;
  }

  short8 x2[2][4];
  const unsigned short* xlane = xb + (size_t)bg * 2048 + q * 128 + l15 * 8;
  {
    const unsigned short* px = xlane + (size_t)t0 * 131072;
    #pragma unroll
    for (int kf = 0; kf < 4; kf++) x2[0][kf] = *(const short8*)(px + kf * 512);
    int t1 = t0 + (tc > 1 ? 1 : 0);
    const unsigned short* py = xlane + (size_t)t1 * 131072;
    #pragma unroll
    for (int kf = 0; kf < 4; kf++) x2[1][kf] = *(const short8*)(py + kf * 512);
  }
  __syncthreads();

  unsigned short* opq = wrseq + (size_t)bg * 2048 + cch * 128 + q * 32 + cj;
  unsigned int* hbw = (unsigned int*)hb;
  int wdw = (2 * w + (l15 >> 3)) * 64 + ((l15 & 6) >> 1);
  bool wlane = (L & 1) == 0;

  auto step = [&](int s, int pin, int pout) {
    short8 Ah[4];
    #pragma unroll
    for (int kf = 0; kf < 4; kf++)
      Ah[kf] = *(const short8*)&hb[pin * 2048 + (kf * 4 + q) * 128 + l15 * 8];

    // h-side MFMAs FIRST (critical path)
    float4v rh = (float4v){0.f,0.f,0.f,0.f}, zh = rh, nh = rh;
    #pragma unroll
    for (int kf = 0; kf < 4; kf++) rh = __builtin_amdgcn_mfma_f32_16x16x32_bf16(Ah[kf], Wh[0][kf], rh, 0,0,0);
    #pragma unroll
    for (int kf = 0; kf < 4; kf++) zh = __builtin_amdgcn_mfma_f32_16x16x32_bf16(Ah[kf], Wh[1][kf], zh, 0,0,0);
    #pragma unroll
    for (int kf = 0; kf < 4; kf++) nh = __builtin_amdgcn_mfma_f32_16x16x32_bf16(Ah[kf], Wh[2][kf], nh, 0,0,0);

    // x-side MFMAs (operands in registers)
    float4v rx = (float4v){0.f,0.f,0.f,0.f}, zx = rx, nx = rx;
    #pragma unroll
    for (int kf = 0; kf < 4; kf++) rx = __builtin_amdgcn_mfma_f32_16x16x32_bf16(x2[pin][kf], Wi[0][kf], rx, 0,0,0);
    #pragma unroll
    for (int kf = 0; kf < 4; kf++) zx = __builtin_amdgcn_mfma_f32_16x16x32_bf16(x2[pin][kf], Wi[1][kf], zx, 0,0,0);
    #pragma unroll
    for (int kf = 0; kf < 4; kf++) nx = __builtin_amdgcn_mfma_f32_16x16x32_bf16(x2[pin][kf], Wi[2][kf], nx, 0,0,0);

    // refill this x buffer for step s+2
    {
      int t2 = t0 + (s + 2 < tc ? s + 2 : tc - 1);
      const unsigned short* px = xlane + (size_t)t2 * 131072;
      #pragma unroll
      for (int kf = 0; kf < 4; kf++) x2[pin][kf] = *(const short8*)(px + kf * 512);
    }

    unsigned int* hbo = hbw + pout * 1024 + wdw;
    #pragma unroll
    for (int r = 0; r < 4; r++) {
      float er = __expf(-(rh[r] + rx[r] + br));
      float ez = __expf(-(zh[r] + zx[r] + bz));
      float pr = 1.0f + er, pz = 1.0f + ez;
      float inv = __builtin_amdgcn_rcpf(pr * pz);
      float rr = pz * inv;
      float zz = pr * inv;
      float y  = nx[r] + bin + rr * (nh[r] + bnh);
      float em = __expf(-2.0f * y);
      float nn = 2.0f * __builtin_amdgcn_rcpf(1.0f + em) - 1.0f;
      float hn = nn + zz * (hold[r] - nn);
      hold[r] = hn;
      unsigned short hu = f2bf(hn);
      opq[r * 8] = hu;
      unsigned int hv = (unsigned int)hu;
      unsigned int ov = (unsigned int)__shfl_xor((int)hv, 1);
      if (wlane) hbo[(4 * q + r) * 4] = hv | (ov << 16);
    }
    opq += 131072;
    LDS_BARRIER();
  };

  int s = 0;
  for (; s + 1 < tc; s += 2) { step(s, 0, 1); step(s + 1, 1, 0); }
  if (s < tc) step(s, 0, 1);
}

// ================= epilogue: score + cum for one chunk, 16 b-rows/block ======
__device__ __forceinline__ void epilogue_body(
    unsigned short* hlL, float* scF4,        // LDS: 10*2048 shorts, 4*800 floats
    const unsigned short* __restrict__ hl_rd,
    const unsigned short* __restrict__ hg_rd,
    const unsigned short* __restrict__ a12,
    const float* __restrict__ v1,
    const int* __restrict__ lengths,
    float* __restrict__ cum, float* __restrict__ out,
    int e, int tc, int bg, int tid)
{
  int w = tid >> 6, L = tid & 63, l15 = L & 15, q = L >> 4;
  int ch = w & 3;                // column half: n-tiles {2ch, 2ch+1}
  int tst = w >> 2;              // t stride-2 offset

  // B-fragments (A1^T, A2^T) for this wave's 2 n-tiles, register-resident
  short8 B1[2][4], B2[2][4];
  float v1v[2];
  #pragma unroll
  for (int ntl = 0; ntl < 2; ntl++) {
    int g = (2 * ch + ntl) * 16 + l15;
    #pragma unroll
    for (int kf = 0; kf < 4; kf++) {
      B1[ntl][kf] = *(const short8*)(a12 + (size_t)g * 128 + kf * 32 + q * 8);
      B2[ntl][kf] = *(const short8*)(a12 + 16384 + (size_t)g * 128 + kf * 32 + q * 8);
    }
    v1v[ntl] = v1[g];
  }

  // score phase: each wave covers its 32 cols for t = tst, tst+2, ...
  for (int t = tst; t < tc; t += 2) {
    size_t base = (size_t)t * 131072 + (size_t)bg * 2048 + q * 128 + l15 * 8;
    short8 Fl[4], Fg[4];
    #pragma unroll
    for (int kf = 0; kf < 4; kf++) {
      Fl[kf] = *(const short8*)(hl_rd + base + kf * 512);
      Fg[kf] = *(const short8*)(hg_rd + base + kf * 512);
    }
    float4v acc[2];
    #pragma unroll
    for (int ntl = 0; ntl < 2; ntl++) {
      float4v a = (float4v){0.f, 0.f, 0.f, 0.f};
      #pragma unroll
      for (int kf = 0; kf < 4; kf++)
        a = __builtin_amdgcn_mfma_f32_16x16x32_bf16(Fl[kf], B1[ntl][kf], a, 0, 0, 0);
      #pragma unroll
      for (int kf = 0; kf < 4; kf++)
        a = __builtin_amdgcn_mfma_f32_16x16x32_bf16(Fg[kf], B2[ntl][kf], a, 0, 0, 0);
      acc[ntl] = a;
    }
    #pragma unroll
    for (int r = 0; r < 4; r++) {
      float s = v1v[0] * sigm(acc[0][r]) + v1v[1] * sigm(acc[1][r]);
      s += __shfl_xor(s, 1, 16);
      s += __shfl_xor(s, 2, 16);
      s += __shfl_xor(s, 4, 16);
      s += __shfl_xor(s, 8, 16);
      if (l15 == 0) scF4[ch * 800 + t * 16 + q * 4 + r] = s;
    }
  }
  __syncthreads();
  // reduce the 4 column-half partials
  for (int i = tid; i < tc * 16; i += 512)
    scF4[i] = scF4[i] + scF4[800 + i] + scF4[1600 + i] + scF4[2400 + i];

  // cum phase: 2048 (b,j) pairs over 512 threads (4 each)
  float cacc[4]; int capv[4], bl4[4], j4[4], bidx[4];
  #pragma unroll
  for (int k = 0; k < 4; k++) {
    int pi = tid + k * 512;
    int bl = pi & 15, j = (pi >> 4) & 127;
    bl4[k] = bl; j4[k] = j;
    int b = bg * 16 + bl; bidx[k] = b;
    cacc[k] = cum[(size_t)b * 128 + j];
    capv[k] = lengths[b] - 4;
  }
  int t0g = e * tc;
  for (int seg = 0; seg < tc; seg += 10) {
    int len = (tc - seg < 10) ? (tc - seg) : 10;
    __syncthreads();                       // also orders the scF4 reduce (first iter)
    for (int f8 = tid; f8 < len * 256; f8 += 512) {
      int tt = f8 >> 8, idx = f8 & 255;
      *(short8*)&hlL[tt * 2048 + idx * 8] =
          *(const short8*)(hl_rd + (size_t)(seg + tt) * 131072 + (size_t)bg * 2048 + idx * 8);
    }
    __syncthreads();
    for (int tt = 0; tt < len; tt++) {
      int t = seg + tt;
      #pragma unroll
      for (int k = 0; k < 4; k++) {
        int fj = (j4[k] >> 3) * 128 + bl4[k] * 8 + (j4[k] & 7);
        float h = bf2f(hlL[tt * 2048 + fj]);
        cacc[k] += scF4[t * 16 + bl4[k]] * h;
        int d = (t0g + t) - capv[k];
        if ((unsigned)d < 4u) {
          float hgv = bf2f(hg_rd[(size_t)t * 131072 + (size_t)bg * 2048 + fj]);
          out[((size_t)bidx[k] * 4 + d) * 128 + j4[k]] = cacc[k] + hgv;
        }
      }
    }
  }
  #pragma unroll
  for (int k = 0; k < 4; k++)
    cum[(size_t)bidx[k] * 128 + j4[k]] = cacc[k];
}

// ================= K_pre: zero carries/cum, cast A1/A2, xcast chunk 0 ========
__global__ __launch_bounds__(512) void k_pre(const float* __restrict__ x,
                                             unsigned short* __restrict__ xb,
                                             unsigned short* hl_slot1, unsigned short* hg_slot1,
                                             float* cum,
                                             const float* A1, const float* A2,
                                             unsigned short* a12, int tc)
{
  int i = blockIdx.x * 512 + threadIdx.x;   // grid 256 -> 131072 threads
  hl_slot1[i] = 0;
  hg_slot1[i] = 0;
  cum[i] = 0.0f;
  if (i < 32768) a12[i] = f2bf((i < 16384) ? A1[i] : A2[i - 16384]);
  int items = tc * 16384;
  for (int i8 = i; i8 < items; i8 += 131072) {
    int t = i8 >> 14, rem = i8 & 16383, b = rem >> 4, chn = rem & 15;
    const float4* xf = (const float4*)(x + (size_t)t * 131072 + (size_t)b * 128 + chn * 8);
    float4 a = xf[0], bb = xf[1];
    short8 o;
    o[0]=(short)f2bf(a.x); o[1]=(short)f2bf(a.y); o[2]=(short)f2bf(a.z); o[3]=(short)f2bf(a.w);
    o[4]=(short)f2bf(bb.x); o[5]=(short)f2bf(bb.y); o[6]=(short)f2bf(bb.z); o[7]=(short)f2bf(bb.w);
    *(short8*)(xb + (size_t)t * 131072 + (size_t)(b >> 4) * 2048 + chn * 128 + (b & 15) * 8) = o;
  }
}

// ================= K_combo: scan(c) + epilogue(c-1) + xcast(c+1) =============
__global__ __launch_bounds__(512, 2) void k_combo(
    const float* __restrict__ x, unsigned short* __restrict__ xb,
    const float* __restrict__ Wih_g, const float* __restrict__ Whh_g,
    const float* __restrict__ bih_g, const float* __restrict__ bhh_g,
    const float* __restrict__ Wih_l, const float* __restrict__ Whh_l,
    const float* __restrict__ bih_l, const float* __restrict__ bhh_l,
    const unsigned short* __restrict__ a12, const float* __restrict__ v1,
    const int* __restrict__ lengths, float* __restrict__ cum, float* __restrict__ out,
    unsigned short* hlA, unsigned short* hgA,
    unsigned short* hlB, unsigned short* hgB,
    int c, int tc, int nch)
{
  __shared__ __align__(16) unsigned short hb[2 * 2048];        // scan
  __shared__ __align__(16) unsigned short hlL[10 * 2048];      // epilogue
  __shared__ float scF4[4 * 800];                              // epilogue
  int bid = blockIdx.x, tid = threadIdx.x;

  if (bid < 128) {
    int p = c & 1;
    unsigned short* hl_wr = p ? hlB : hlA;
    unsigned short* hg_wr = p ? hgB : hgA;
    const unsigned short* hl_pv = p ? hlA : hlB;
    const unsigned short* hg_pv = p ? hgA : hgB;
    int gru = bid & 1;
    scan_body(hb, xb, Wih_g, Whh_g, bih_g, bhh_g, Wih_l, Whh_l, bih_l, bhh_l,
              gru ? hl_wr : hg_wr, gru ? hl_pv : hg_pv, tc, c * tc, bid, tid);
  } else if (bid < 192) {
    if (c == 0) return;
    int e = c - 1, pe = e & 1;
    epilogue_body(hlL, scF4, pe ? hlB : hlA, pe ? hgB : hgA, a12, v1,
                  lengths, cum, out, e, tc, bid - 128, tid);
  } else {
    int cx = c + 1;
    if (cx >= nch) return;
    int gtid = (bid - 192) * 512 + tid;     // 0..32767
    int items = tc * 16384;
    for (int i8 = gtid; i8 < items; i8 += 32768) {
      int tl = i8 >> 14, rem = i8 & 16383, b = rem >> 4, chn = rem & 15;
      int t = cx * tc + tl;
      const float4* xf = (const float4*)(x + (size_t)t * 131072 + (size_t)b * 128 + chn * 8);
      float4 a = xf[0], bb = xf[1];
      short8 o;
      o[0]=(short)f2bf(a.x); o[1]=(short)f2bf(a.y); o[2]=(short)f2bf(a.z); o[3]=(short)f2bf(a.w);
      o[4]=(short)f2bf(bb.x); o[5]=(short)f2bf(bb.y); o[6]=(short)f2bf(bb.z); o[7]=(short)f2bf(bb.w);
      *(short8*)(xb + (size_t)t * 131072 + (size_t)(b >> 4) * 2048 + chn * 128 + (b & 15) * 8) = o;
    }
  }
}

// ================= K_epi: final chunk's epilogue =============================
__global__ __launch_bounds__(512, 2) void k_epi(
    const unsigned short* __restrict__ a12, const float* __restrict__ v1,
    const int* __restrict__ lengths, float* __restrict__ cum, float* __restrict__ out,
    unsigned short* hlA, unsigned short* hgA,
    unsigned short* hlB, unsigned short* hgB,
    int e, int tc)
{
  __shared__ __align__(16) unsigned short hlL[10 * 2048];
  __shared__ float scF4[4 * 800];
  int pe = e & 1;
  epilogue_body(hlL, scF4, pe ? hlB : hlA, pe ? hgB : hgA, a12, v1,
                lengths, cum, out, e, tc, blockIdx.x, threadIdx.x);
}

// ---------------- launch ----------------
extern "C" void kernel_launch(void* const* d_in, const int* in_sizes, int n_in,
                              void* d_out, int out_size, void* d_ws, size_t ws_size,
                              hipStream_t stream)
{
  const float* x     = (const float*)d_in[0];
  const int* lengths = (const int*)d_in[1];
  const float* Wih_g = (const float*)d_in[2];
  const float* Whh_g = (const float*)d_in[3];
  const float* bih_g = (const float*)d_in[4];
  const float* bhh_g = (const float*)d_in[5];
  const float* Wih_l = (const float*)d_in[6];
  const float* Whh_l = (const float*)d_in[7];
  const float* bih_l = (const float*)d_in[8];
  const float* bhh_l = (const float*)d_in[9];
  const float* A1    = (const float*)d_in[10];
  const float* A2    = (const float*)d_in[11];
  const float* v1    = (const float*)d_in[12];
  float* out = (float*)d_out;

  const size_t XB = (size_t)200 * 1024 * 128 * 2;   // xb bf16, full T
  const size_t fixed = 65536 + 524288 + XB;         // a12 + cum + xb
  const int cands[6] = {50, 25, 10, 5, 2, 1};
  int tc = 0;
  for (int i = 0; i < 6; i++) {
    int T = cands[i];
    size_t CH = (size_t)T * 1024 * 128 * 2;         // one parity of one of hl/hg
    if (fixed + 4 * CH <= ws_size) { tc = T; break; }
  }
  if (!tc) return;
  size_t CH = (size_t)tc * 1024 * 128 * 2;

  char* wsb = (char*)d_ws;
  size_t o = 0;
  unsigned short* a12 = (unsigned short*)(wsb + o); o += 65536;
  float* cum          = (float*)(wsb + o);          o += 524288;
  unsigned short* xb  = (unsigned short*)(wsb + o); o += XB;
  unsigned short* hlA = (unsigned short*)(wsb + o); o += CH;
  unsigned short* hgA = (unsigned short*)(wsb + o); o += CH;
  unsigned short* hlB = (unsigned short*)(wsb + o); o += CH;
  unsigned short* hgB = (unsigned short*)(wsb + o); o += CH;

  // chunk 0 reads carry from parity-1 (B) slot tc-1: zero it
  unsigned short* hl_slot1 = hlB + (size_t)(tc - 1) * 131072;
  unsigned short* hg_slot1 = hgB + (size_t)(tc - 1) * 131072;

  int nch = 200 / tc;
  k_pre<<<256, 512, 0, stream>>>(x, xb, hl_slot1, hg_slot1, cum, A1, A2, a12, tc);
  for (int c = 0; c < nch; c++) {
    k_combo<<<256, 512, 0, stream>>>(x, xb, Wih_g, Whh_g, bih_g, bhh_g,
                                     Wih_l, Whh_l, bih_l, bhh_l,
                                     a12, v1, lengths, cum, out,
                                     hlA, hgA, hlB, hgB, c, tc, nch);
  }
  k_epi<<<64, 512, 0, stream>>>(a12, v1, lengths, cum, out,
                                hlA, hgA, hlB, hgB, nch - 1, tc);
}